// Round 1
// baseline (745.255 us; speedup 1.0000x reference)
//
#include <hip/hip_runtime.h>
#include <hip/hip_bf16.h>

// NaryTreeLSTM  B=32768, K=4, I=256, H=256
// DTYPE MODEL (verified): inputs fp32, outputs fp32, bf16-scale threshold
// => bf16 MFMA pipeline, fp32 accum, fp32 out stores.
//
// ROUND-6: root_k restructured t=2 -> t=1 (16 rows/wave).
//   Old shape needed ~200 VGPRs (ax+ah frags alone = 128) but reported 128
//   => compiler spilled/remat'd A-frags every ctl iter (WRITE_SIZE 91MB vs
//   64MB ideal), and grid 512 blocks capped occupancy at 8 waves/CU (23%).
//   New: 64 rows/block, grid 1024 blocks, __launch_bounds__(256,4):
//   frags 64 VGPR, peak ~125-135 -> no spill, 16 waves/CU (50%).
//   cc gathers prefetched at top of each ctl iter (hide ~600cy under MFMA).
// child: round-5 streaming structure unchanged (next target; its counters
//   will surface in top-5 once root drops below it).
//
// ws: cc [B][H][K] bf16, hsum [B][H] bf16, bf16 weight copies.

#define BB 32768
#define KK 4
#define II 256
#define HH 256

typedef __bf16 bf16x8 __attribute__((ext_vector_type(8)));
typedef __bf16 bf16x4 __attribute__((ext_vector_type(4)));
typedef float f32x4 __attribute__((ext_vector_type(4)));

#define MFMA16(a, b, c) __builtin_amdgcn_mfma_f32_16x16x32_bf16(a, b, c, 0, 0, 0)

static __device__ __forceinline__ float fsig(float x) {
    return 1.0f / (1.0f + __expf(-x));
}
static __device__ __forceinline__ float ftanhf(float x) {
    float e = __expf(2.0f * x);
    return 1.0f - 2.0f / (e + 1.0f);
}

static __device__ __forceinline__ bf16x8 cvt8v(float4 f0, float4 f1) {
    bf16x8 v;
    v[0] = (__bf16)f0.x; v[1] = (__bf16)f0.y; v[2] = (__bf16)f0.z; v[3] = (__bf16)f0.w;
    v[4] = (__bf16)f1.x; v[5] = (__bf16)f1.y; v[6] = (__bf16)f1.z; v[7] = (__bf16)f1.w;
    return v;
}
static __device__ __forceinline__ bf16x8 cvt8(const float* __restrict__ p) {
    return cvt8v(((const float4*)p)[0], ((const float4*)p)[1]);
}

// ---------------- Kernel 0: fp32 -> bf16 weight conversion ----------------
struct CvtArgs {
    const float* src[8];
    __bf16* dst[8];
    int n[8];
};
__global__ __launch_bounds__(256) void cvt_k(CvtArgs a) {
    const int t = blockIdx.y;
    const int i = (blockIdx.x * 256 + threadIdx.x) * 4;
    if (i < a.n[t]) {
        float4 f = *(const float4*)(a.src[t] + i);
        bf16x4 v;
        v[0] = (__bf16)f.x; v[1] = (__bf16)f.y; v[2] = (__bf16)f.z; v[3] = (__bf16)f.w;
        *(bf16x4*)(a.dst[t] + i) = v;
    }
}

// ---------------- Kernel 1: child gates, streaming ----------------
// grid.x = 1024 linear: rowchunk = bid>>1 (256 child rows), cthalf = bid&1.
// LDS row stride 264 elems (528 B): 16B-superbank stride 33 -> uniform
// 8-lane/superbank for both ds_write (staging) and ds_read_b128 (frags).
#define ROWSTR 264
__global__ __launch_bounds__(512, 2) void child_gates_k(
    const float* __restrict__ child_x,
    const __bf16* __restrict__ Wi, const __bf16* __restrict__ Wo,
    const __bf16* __restrict__ Wu,
    const float* __restrict__ bi, const float* __restrict__ bo,
    const float* __restrict__ bu,
    __bf16* __restrict__ cc, __bf16* __restrict__ hsum)
{
    const int tid  = threadIdx.x;
    const int wave = tid >> 6;
    const int lane = tid & 63;
    const int l16  = lane & 15;
    const int quad = lane >> 4;
    const int rowchunk = blockIdx.x >> 1;           // 256 child rows each
    const int ct   = (blockIdx.x & 1) * 8 + wave;   // this wave's col-tile
    const int n    = ct * 16 + l16;

    // --- weight fragments for this ct, held for the whole kernel (96 VGPR)
    bf16x8 w[3][8];
    {
        const int base = n * II + quad * 8;
#pragma unroll
        for (int ks = 0; ks < 8; ++ks) {
            w[0][ks] = *(const bf16x8*)(Wi + base + ks * 32);
            w[1][ks] = *(const bf16x8*)(Wo + base + ks * 32);
            w[2][ks] = *(const bf16x8*)(Wu + base + ks * 32);
        }
    }
    const float bin = bi[n], bon = bo[n], bun = bu[n];

    __shared__ __bf16 As[2][16 * ROWSTR];

    // staging map: 512 thr, thread -> (row = tid>>5, col8 = (tid&31)*8)
    const int srow = tid >> 5;
    const int scol = (tid & 31) * 8;
    const float* gbase = child_x + ((size_t)rowchunk * 256 + srow) * II + scol;

    float4 f0 = ((const float4*)gbase)[0];
    float4 f1 = ((const float4*)gbase)[1];
    *(bf16x8*)(&As[0][srow * ROWSTR + scol]) = cvt8v(f0, f1);
    __syncthreads();

    for (int t = 0; t < 16; ++t) {
        float4 g0, g1;
        if (t < 15) {   // issue t+1 global loads now; consume after compute
            const float* gp = gbase + (size_t)(t + 1) * 16 * II;
            g0 = ((const float4*)gp)[0];
            g1 = ((const float4*)gp)[1];
        }

        // --- compute tile t from LDS
        const __bf16* ap = &As[t & 1][l16 * ROWSTR + quad * 8];
        f32x4 ai = {0.f,0.f,0.f,0.f}, ao = {0.f,0.f,0.f,0.f}, au = {0.f,0.f,0.f,0.f};
#pragma unroll
        for (int ks = 0; ks < 8; ++ks) {
            bf16x8 a = *(const bf16x8*)(ap + ks * 32);
            ai = MFMA16(a, w[0][ks], ai);
            ao = MFMA16(a, w[1][ks], ao);
            au = MFMA16(a, w[2][ks], au);
        }

        // --- epilogue: lane's 4 regs = 4 children of b = rowchunk*64+t*4+quad
        {
            const int b = rowchunk * 64 + t * 4 + quad;
            float chs = 0.f;
            bf16x4 ccv4;
#pragma unroll
            for (int r = 0; r < 4; ++r) {
                float civ = fsig(ai[r] + bin);
                float cov = fsig(ao[r] + bon);
                float cuv = ftanhf(au[r] + bun);
                float ccv = civ * cuv;
                chs += cov * ftanhf(ccv);
                ccv4[r] = (__bf16)ccv;
            }
            *(bf16x4*)(cc + ((size_t)b * HH + n) * KK) = ccv4;
            hsum[(size_t)b * HH + n] = (__bf16)chs;
        }

        if (t < 15)
            *(bf16x8*)(&As[(t + 1) & 1][srow * ROWSTR + scol]) = cvt8v(g0, g1);
        __syncthreads();
    }
}

// ---------------- Kernel 2: root gates ----------------
// t=1: 16 rows/wave, 64 rows/block, grid (BB/64, 2) = 1024 blocks.
// A-frags 64 VGPR; launch_bounds(256,4) targets 4 waves/SIMD (50% occ).
// cc gathers prefetched per ctl iter, hidden under pass-1/2 MFMA.
__global__ __launch_bounds__(256, 4) void root_k(
    const float* __restrict__ x,
    const __bf16* __restrict__ Wi, const __bf16* __restrict__ Wf,
    const __bf16* __restrict__ Wo, const __bf16* __restrict__ Wu,
    const __bf16* __restrict__ Ui, const __bf16* __restrict__ Uo,
    const __bf16* __restrict__ Uu, const __bf16* __restrict__ WfK,
    const float* __restrict__ bi, const float* __restrict__ bf_,
    const float* __restrict__ bo, const float* __restrict__ bu,
    const __bf16* __restrict__ cc, const __bf16* __restrict__ hsum,
    float* __restrict__ out)
{
    const int lane = threadIdx.x & 63;
    const int wave = threadIdx.x >> 6;
    const int l16  = lane & 15;
    const int quad = lane >> 4;
    const int row0 = blockIdx.x * 64 + wave * 16;   // 16 b-rows per wave
    const int ctbase = blockIdx.y * 8;

    // A-fragments for this wave's 16 rows, held across all 8 ctl (64 VGPR)
    bf16x8 ax[8], ah[8];
    {
        const float*  xp = x    + (size_t)(row0 + l16) * II + quad * 8;
        const __bf16* hp = hsum + (size_t)(row0 + l16) * HH + quad * 8;
#pragma unroll
        for (int ks = 0; ks < 8; ++ks) {
            ax[ks] = cvt8(xp + ks * 32);
            ah[ks] = *(const bf16x8*)(hp + ks * 32);
        }
    }

    for (int ctl = 0; ctl < 8; ++ctl) {
        const int n = (ctbase + ctl) * 16 + l16;
        const float bin = bi[n], bfn = bf_[n], bon = bo[n], bun = bu[n];
        const int wo = n * II + quad * 8;

        // ---- prefetch cc gathers for this ctl (hide L3/HBM latency) ----
        bf16x4 cv4[4];
#pragma unroll
        for (int r = 0; r < 4; ++r) {
            const int b = row0 + quad * 4 + r;
            cv4[r] = *(const bf16x4*)(cc + ((size_t)b * HH + n) * KK);
        }

        // ---- pass 1: i, o, u ----
        f32x4 ai = {0.f,0.f,0.f,0.f}, ao = {0.f,0.f,0.f,0.f}, au = {0.f,0.f,0.f,0.f};
#pragma unroll
        for (int ks = 0; ks < 8; ++ks) {
            const int o = wo + ks * 32;
            bf16x8 bwi = *(const bf16x8*)(Wi + o);
            bf16x8 bui = *(const bf16x8*)(Ui + o);
            bf16x8 bwo = *(const bf16x8*)(Wo + o);
            bf16x8 buo = *(const bf16x8*)(Uo + o);
            bf16x8 bwu = *(const bf16x8*)(Wu + o);
            bf16x8 buu = *(const bf16x8*)(Uu + o);
            ai = MFMA16(ax[ks], bwi, ai);
            ai = MFMA16(ah[ks], bui, ai);
            ao = MFMA16(ax[ks], bwo, ao);
            ao = MFMA16(ah[ks], buo, ao);
            au = MFMA16(ax[ks], bwu, au);
            au = MFMA16(ah[ks], buu, au);
        }
        float iv[4], ov[4], uv[4];
#pragma unroll
        for (int r = 0; r < 4; ++r) {
            iv[r] = fsig(ai[r] + bin);
            ov[r] = fsig(ao[r] + bon);
            uv[r] = ftanhf(au[r] + bun);
        }

        // ---- pass 2: f-family ----
        f32x4 axf = {0.f,0.f,0.f,0.f};
        f32x4 af0 = {0.f,0.f,0.f,0.f}, af1 = {0.f,0.f,0.f,0.f};
        f32x4 af2 = {0.f,0.f,0.f,0.f}, af3 = {0.f,0.f,0.f,0.f};
#pragma unroll
        for (int ks = 0; ks < 8; ++ks) {
            const int o = wo + ks * 32;
            bf16x8 bwf = *(const bf16x8*)(Wf + o);
            bf16x8 bk0 = *(const bf16x8*)(WfK + 0 * HH * II + o);
            bf16x8 bk1 = *(const bf16x8*)(WfK + 1 * HH * II + o);
            bf16x8 bk2 = *(const bf16x8*)(WfK + 2 * HH * II + o);
            bf16x8 bk3 = *(const bf16x8*)(WfK + 3 * HH * II + o);
            axf = MFMA16(ax[ks], bwf, axf);
            af0 = MFMA16(ah[ks], bk0, af0);
            af1 = MFMA16(ah[ks], bk1, af1);
            af2 = MFMA16(ah[ks], bk2, af2);
            af3 = MFMA16(ah[ks], bk3, af3);
        }

        // ---- epilogue: fp32 stores ----
#pragma unroll
        for (int r = 0; r < 4; ++r) {
            const int b = row0 + quad * 4 + r;
            const float xfv = axf[r] + bfn;
            float cv = iv[r] * uv[r];
            cv += fsig(xfv + af0[r]) * (float)cv4[r][0];
            cv += fsig(xfv + af1[r]) * (float)cv4[r][1];
            cv += fsig(xfv + af2[r]) * (float)cv4[r][2];
            cv += fsig(xfv + af3[r]) * (float)cv4[r][3];
            float hv = ov[r] * ftanhf(cv);
            out[(size_t)b * HH + n] = hv;                    // h
            out[(size_t)BB * HH + (size_t)b * HH + n] = cv;  // c
        }
    }
}

extern "C" void kernel_launch(void* const* d_in, const int* in_sizes, int n_in,
                              void* d_out, int out_size, void* d_ws, size_t ws_size,
                              hipStream_t stream) {
    const float* x    = (const float*)d_in[0];
    const float* cx   = (const float*)d_in[1];
    const float* Wi   = (const float*)d_in[2];
    const float* bi   = (const float*)d_in[3];
    const float* Wf   = (const float*)d_in[4];
    const float* bf_  = (const float*)d_in[5];
    const float* Wo   = (const float*)d_in[6];
    const float* bo   = (const float*)d_in[7];
    const float* Wu   = (const float*)d_in[8];
    const float* bu   = (const float*)d_in[9];
    const float* Ui   = (const float*)d_in[10];
    const float* Uo   = (const float*)d_in[11];
    const float* Uu   = (const float*)d_in[12];
    const float* WfK  = (const float*)d_in[13];

    __bf16* cc = (__bf16*)d_ws;                     // [B][H][K]
    __bf16* hs = cc + (size_t)BB * KK * HH;         // [B][H]
    __bf16* wb = hs + (size_t)BB * HH;              // bf16 weight block
    __bf16 *Wi_b = wb,            *Wf_b = Wi_b + HH * II, *Wo_b = Wf_b + HH * II,
           *Wu_b = Wo_b + HH * II, *Ui_b = Wu_b + HH * II, *Uo_b = Ui_b + HH * HH,
           *Uu_b = Uo_b + HH * HH, *WfK_b = Uu_b + HH * HH;  // WfK: K*H*H

    CvtArgs ca;
    ca.src[0] = Wi;  ca.dst[0] = Wi_b;  ca.n[0] = HH * II;
    ca.src[1] = Wf;  ca.dst[1] = Wf_b;  ca.n[1] = HH * II;
    ca.src[2] = Wo;  ca.dst[2] = Wo_b;  ca.n[2] = HH * II;
    ca.src[3] = Wu;  ca.dst[3] = Wu_b;  ca.n[3] = HH * II;
    ca.src[4] = Ui;  ca.dst[4] = Ui_b;  ca.n[4] = HH * HH;
    ca.src[5] = Uo;  ca.dst[5] = Uo_b;  ca.n[5] = HH * HH;
    ca.src[6] = Uu;  ca.dst[6] = Uu_b;  ca.n[6] = HH * HH;
    ca.src[7] = WfK; ca.dst[7] = WfK_b; ca.n[7] = KK * HH * HH;

    cvt_k<<<dim3(KK * HH * HH / 1024, 8), dim3(256), 0, stream>>>(ca);
    child_gates_k<<<dim3(1024), dim3(512), 0, stream>>>(
        cx, Wi_b, Wo_b, Wu_b, bi, bo, bu, cc, hs);
    root_k<<<dim3(BB / 64, 2), dim3(256), 0, stream>>>(
        x, Wi_b, Wf_b, Wo_b, Wu_b, Ui_b, Uo_b, Uu_b, WfK_b,
        bi, bf_, bo, bu, cc, hs, (float*)d_out);
}

// Round 3
// 695.822 us; speedup vs baseline: 1.0710x; 1.0710x over previous
//
#include <hip/hip_runtime.h>
#include <hip/hip_bf16.h>

// NaryTreeLSTM  B=32768, K=4, I=256, H=256
// DTYPE MODEL (verified): inputs fp32, outputs fp32, bf16-scale threshold
// => bf16 MFMA pipeline, fp32 accum, fp32 out stores.
//
// ROUND-8: RERUN of round-7 (container failed twice = infra, not kernel).
// root_k remat fix. R6 counters (VGPR_Count=64, FETCH +126MB,
//   MfmaUtil 4.5%) proved the compiler REMATERIALIZES the ax/ah fragment
//   loads instead of keeping them resident (R5 had the same disease at
//   t=2/128 regs). Fix: t=1 shape + __launch_bounds__(256,3) (170-reg cap,
//   ~160 demand) + opaque asm pins on ax/ah so they cannot be remat'd.
//   Occupancy: VGPR-limited 3 blocks/CU = 12 waves/CU.
// child: byte-identical to R5/R6 (~320us). Its counters will surface in
//   top-5 once root drops below it; fix with evidence next round.
//
// ws: cc [B][H][K] bf16, hsum [B][H] bf16, bf16 weight copies.

#define BB 32768
#define KK 4
#define II 256
#define HH 256

typedef __bf16 bf16x8 __attribute__((ext_vector_type(8)));
typedef __bf16 bf16x4 __attribute__((ext_vector_type(4)));
typedef float f32x4 __attribute__((ext_vector_type(4)));

#define MFMA16(a, b, c) __builtin_amdgcn_mfma_f32_16x16x32_bf16(a, b, c, 0, 0, 0)

static __device__ __forceinline__ float fsig(float x) {
    return 1.0f / (1.0f + __expf(-x));
}
static __device__ __forceinline__ float ftanhf(float x) {
    float e = __expf(2.0f * x);
    return 1.0f - 2.0f / (e + 1.0f);
}

// Opaque register pin: makes the asm the producer of v, so the compiler
// cannot rematerialize the original load on later uses.
static __device__ __forceinline__ void keepv(bf16x8& v) {
    f32x4& f = reinterpret_cast<f32x4&>(v);
    asm volatile("" : "+v"(f));
}

static __device__ __forceinline__ bf16x8 cvt8v(float4 f0, float4 f1) {
    bf16x8 v;
    v[0] = (__bf16)f0.x; v[1] = (__bf16)f0.y; v[2] = (__bf16)f0.z; v[3] = (__bf16)f0.w;
    v[4] = (__bf16)f1.x; v[5] = (__bf16)f1.y; v[6] = (__bf16)f1.z; v[7] = (__bf16)f1.w;
    return v;
}
static __device__ __forceinline__ bf16x8 cvt8(const float* __restrict__ p) {
    return cvt8v(((const float4*)p)[0], ((const float4*)p)[1]);
}

// ---------------- Kernel 0: fp32 -> bf16 weight conversion ----------------
struct CvtArgs {
    const float* src[8];
    __bf16* dst[8];
    int n[8];
};
__global__ __launch_bounds__(256) void cvt_k(CvtArgs a) {
    const int t = blockIdx.y;
    const int i = (blockIdx.x * 256 + threadIdx.x) * 4;
    if (i < a.n[t]) {
        float4 f = *(const float4*)(a.src[t] + i);
        bf16x4 v;
        v[0] = (__bf16)f.x; v[1] = (__bf16)f.y; v[2] = (__bf16)f.z; v[3] = (__bf16)f.w;
        *(bf16x4*)(a.dst[t] + i) = v;
    }
}

// ---------------- Kernel 1: child gates, streaming ----------------
// grid.x = 1024 linear: rowchunk = bid>>1 (256 child rows), cthalf = bid&1.
// LDS row stride 264 elems (528 B): 16B-superbank stride 33 -> uniform
// 8-lane/superbank for both ds_write (staging) and ds_read_b128 (frags).
#define ROWSTR 264
__global__ __launch_bounds__(512, 2) void child_gates_k(
    const float* __restrict__ child_x,
    const __bf16* __restrict__ Wi, const __bf16* __restrict__ Wo,
    const __bf16* __restrict__ Wu,
    const float* __restrict__ bi, const float* __restrict__ bo,
    const float* __restrict__ bu,
    __bf16* __restrict__ cc, __bf16* __restrict__ hsum)
{
    const int tid  = threadIdx.x;
    const int wave = tid >> 6;
    const int lane = tid & 63;
    const int l16  = lane & 15;
    const int quad = lane >> 4;
    const int rowchunk = blockIdx.x >> 1;           // 256 child rows each
    const int ct   = (blockIdx.x & 1) * 8 + wave;   // this wave's col-tile
    const int n    = ct * 16 + l16;

    // --- weight fragments for this ct, held for the whole kernel (96 VGPR)
    bf16x8 w[3][8];
    {
        const int base = n * II + quad * 8;
#pragma unroll
        for (int ks = 0; ks < 8; ++ks) {
            w[0][ks] = *(const bf16x8*)(Wi + base + ks * 32);
            w[1][ks] = *(const bf16x8*)(Wo + base + ks * 32);
            w[2][ks] = *(const bf16x8*)(Wu + base + ks * 32);
        }
    }
    const float bin = bi[n], bon = bo[n], bun = bu[n];

    __shared__ __bf16 As[2][16 * ROWSTR];

    // staging map: 512 thr, thread -> (row = tid>>5, col8 = (tid&31)*8)
    const int srow = tid >> 5;
    const int scol = (tid & 31) * 8;
    const float* gbase = child_x + ((size_t)rowchunk * 256 + srow) * II + scol;

    float4 f0 = ((const float4*)gbase)[0];
    float4 f1 = ((const float4*)gbase)[1];
    *(bf16x8*)(&As[0][srow * ROWSTR + scol]) = cvt8v(f0, f1);
    __syncthreads();

    for (int t = 0; t < 16; ++t) {
        float4 g0, g1;
        if (t < 15) {   // issue t+1 global loads now; consume after compute
            const float* gp = gbase + (size_t)(t + 1) * 16 * II;
            g0 = ((const float4*)gp)[0];
            g1 = ((const float4*)gp)[1];
        }

        // --- compute tile t from LDS
        const __bf16* ap = &As[t & 1][l16 * ROWSTR + quad * 8];
        f32x4 ai = {0.f,0.f,0.f,0.f}, ao = {0.f,0.f,0.f,0.f}, au = {0.f,0.f,0.f,0.f};
#pragma unroll
        for (int ks = 0; ks < 8; ++ks) {
            bf16x8 a = *(const bf16x8*)(ap + ks * 32);
            ai = MFMA16(a, w[0][ks], ai);
            ao = MFMA16(a, w[1][ks], ao);
            au = MFMA16(a, w[2][ks], au);
        }

        // --- epilogue: lane's 4 regs = 4 children of b = rowchunk*64+t*4+quad
        {
            const int b = rowchunk * 64 + t * 4 + quad;
            float chs = 0.f;
            bf16x4 ccv4;
#pragma unroll
            for (int r = 0; r < 4; ++r) {
                float civ = fsig(ai[r] + bin);
                float cov = fsig(ao[r] + bon);
                float cuv = ftanhf(au[r] + bun);
                float ccv = civ * cuv;
                chs += cov * ftanhf(ccv);
                ccv4[r] = (__bf16)ccv;
            }
            *(bf16x4*)(cc + ((size_t)b * HH + n) * KK) = ccv4;
            hsum[(size_t)b * HH + n] = (__bf16)chs;
        }

        if (t < 15)
            *(bf16x8*)(&As[(t + 1) & 1][srow * ROWSTR + scol]) = cvt8v(g0, g1);
        __syncthreads();
    }
}

// ---------------- Kernel 2: root gates ----------------
// t=1: 16 rows/wave, 64 rows/block, grid (BB/64, 2) = 1024 blocks.
// A-frags = 64 VGPR, PINNED via opaque asm (anti-remat). launch_bounds
// (256,3): 170-reg cap fits ~160 demand -> 3 blocks/CU = 12 waves/CU.
// cc gathers prefetched per ctl iter, hidden under pass-1/2 MFMA.
__global__ __launch_bounds__(256, 3) void root_k(
    const float* __restrict__ x,
    const __bf16* __restrict__ Wi, const __bf16* __restrict__ Wf,
    const __bf16* __restrict__ Wo, const __bf16* __restrict__ Wu,
    const __bf16* __restrict__ Ui, const __bf16* __restrict__ Uo,
    const __bf16* __restrict__ Uu, const __bf16* __restrict__ WfK,
    const float* __restrict__ bi, const float* __restrict__ bf_,
    const float* __restrict__ bo, const float* __restrict__ bu,
    const __bf16* __restrict__ cc, const __bf16* __restrict__ hsum,
    float* __restrict__ out)
{
    const int lane = threadIdx.x & 63;
    const int wave = threadIdx.x >> 6;
    const int l16  = lane & 15;
    const int quad = lane >> 4;
    const int row0 = blockIdx.x * 64 + wave * 16;   // 16 b-rows per wave
    const int ctbase = blockIdx.y * 8;

    // A-fragments for this wave's 16 rows, held across all 8 ctl (64 VGPR)
    bf16x8 ax[8], ah[8];
    {
        const float*  xp = x    + (size_t)(row0 + l16) * II + quad * 8;
        const __bf16* hp = hsum + (size_t)(row0 + l16) * HH + quad * 8;
#pragma unroll
        for (int ks = 0; ks < 8; ++ks) {
            ax[ks] = cvt8(xp + ks * 32);
            ah[ks] = *(const bf16x8*)(hp + ks * 32);
        }
    }
    // Pin the fragments in registers: the asm becomes their producer, so
    // the compiler cannot rematerialize the global loads per ctl/ks iter.
#pragma unroll
    for (int ks = 0; ks < 8; ++ks) {
        keepv(ax[ks]);
        keepv(ah[ks]);
    }

    for (int ctl = 0; ctl < 8; ++ctl) {
        const int n = (ctbase + ctl) * 16 + l16;
        const float bin = bi[n], bfn = bf_[n], bon = bo[n], bun = bu[n];
        const int wo = n * II + quad * 8;

        // ---- prefetch cc gathers for this ctl (hide L3/HBM latency) ----
        bf16x4 cv4[4];
#pragma unroll
        for (int r = 0; r < 4; ++r) {
            const int b = row0 + quad * 4 + r;
            cv4[r] = *(const bf16x4*)(cc + ((size_t)b * HH + n) * KK);
        }

        // ---- pass 1: i, o, u ----
        f32x4 ai = {0.f,0.f,0.f,0.f}, ao = {0.f,0.f,0.f,0.f}, au = {0.f,0.f,0.f,0.f};
#pragma unroll
        for (int ks = 0; ks < 8; ++ks) {
            const int o = wo + ks * 32;
            bf16x8 bwi = *(const bf16x8*)(Wi + o);
            bf16x8 bui = *(const bf16x8*)(Ui + o);
            bf16x8 bwo = *(const bf16x8*)(Wo + o);
            bf16x8 buo = *(const bf16x8*)(Uo + o);
            bf16x8 bwu = *(const bf16x8*)(Wu + o);
            bf16x8 buu = *(const bf16x8*)(Uu + o);
            ai = MFMA16(ax[ks], bwi, ai);
            ai = MFMA16(ah[ks], bui, ai);
            ao = MFMA16(ax[ks], bwo, ao);
            ao = MFMA16(ah[ks], buo, ao);
            au = MFMA16(ax[ks], bwu, au);
            au = MFMA16(ah[ks], buu, au);
        }
        float iv[4], ov[4], uv[4];
#pragma unroll
        for (int r = 0; r < 4; ++r) {
            iv[r] = fsig(ai[r] + bin);
            ov[r] = fsig(ao[r] + bon);
            uv[r] = ftanhf(au[r] + bun);
        }

        // ---- pass 2: f-family ----
        f32x4 axf = {0.f,0.f,0.f,0.f};
        f32x4 af0 = {0.f,0.f,0.f,0.f}, af1 = {0.f,0.f,0.f,0.f};
        f32x4 af2 = {0.f,0.f,0.f,0.f}, af3 = {0.f,0.f,0.f,0.f};
#pragma unroll
        for (int ks = 0; ks < 8; ++ks) {
            const int o = wo + ks * 32;
            bf16x8 bwf = *(const bf16x8*)(Wf + o);
            bf16x8 bk0 = *(const bf16x8*)(WfK + 0 * HH * II + o);
            bf16x8 bk1 = *(const bf16x8*)(WfK + 1 * HH * II + o);
            bf16x8 bk2 = *(const bf16x8*)(WfK + 2 * HH * II + o);
            bf16x8 bk3 = *(const bf16x8*)(WfK + 3 * HH * II + o);
            axf = MFMA16(ax[ks], bwf, axf);
            af0 = MFMA16(ah[ks], bk0, af0);
            af1 = MFMA16(ah[ks], bk1, af1);
            af2 = MFMA16(ah[ks], bk2, af2);
            af3 = MFMA16(ah[ks], bk3, af3);
        }

        // ---- epilogue: fp32 stores ----
#pragma unroll
        for (int r = 0; r < 4; ++r) {
            const int b = row0 + quad * 4 + r;
            const float xfv = axf[r] + bfn;
            float cv = iv[r] * uv[r];
            cv += fsig(xfv + af0[r]) * (float)cv4[r][0];
            cv += fsig(xfv + af1[r]) * (float)cv4[r][1];
            cv += fsig(xfv + af2[r]) * (float)cv4[r][2];
            cv += fsig(xfv + af3[r]) * (float)cv4[r][3];
            float hv = ov[r] * ftanhf(cv);
            out[(size_t)b * HH + n] = hv;                    // h
            out[(size_t)BB * HH + (size_t)b * HH + n] = cv;  // c
        }
    }
}

extern "C" void kernel_launch(void* const* d_in, const int* in_sizes, int n_in,
                              void* d_out, int out_size, void* d_ws, size_t ws_size,
                              hipStream_t stream) {
    const float* x    = (const float*)d_in[0];
    const float* cx   = (const float*)d_in[1];
    const float* Wi   = (const float*)d_in[2];
    const float* bi   = (const float*)d_in[3];
    const float* Wf   = (const float*)d_in[4];
    const float* bf_  = (const float*)d_in[5];
    const float* Wo   = (const float*)d_in[6];
    const float* bo   = (const float*)d_in[7];
    const float* Wu   = (const float*)d_in[8];
    const float* bu   = (const float*)d_in[9];
    const float* Ui   = (const float*)d_in[10];
    const float* Uo   = (const float*)d_in[11];
    const float* Uu   = (const float*)d_in[12];
    const float* WfK  = (const float*)d_in[13];

    __bf16* cc = (__bf16*)d_ws;                     // [B][H][K]
    __bf16* hs = cc + (size_t)BB * KK * HH;         // [B][H]
    __bf16* wb = hs + (size_t)BB * HH;              // bf16 weight block
    __bf16 *Wi_b = wb,            *Wf_b = Wi_b + HH * II, *Wo_b = Wf_b + HH * II,
           *Wu_b = Wo_b + HH * II, *Ui_b = Wu_b + HH * II, *Uo_b = Ui_b + HH * HH,
           *Uu_b = Uo_b + HH * HH, *WfK_b = Uu_b + HH * HH;  // WfK: K*H*H

    CvtArgs ca;
    ca.src[0] = Wi;  ca.dst[0] = Wi_b;  ca.n[0] = HH * II;
    ca.src[1] = Wf;  ca.dst[1] = Wf_b;  ca.n[1] = HH * II;
    ca.src[2] = Wo;  ca.dst[2] = Wo_b;  ca.n[2] = HH * II;
    ca.src[3] = Wu;  ca.dst[3] = Wu_b;  ca.n[3] = HH * II;
    ca.src[4] = Ui;  ca.dst[4] = Ui_b;  ca.n[4] = HH * HH;
    ca.src[5] = Uo;  ca.dst[5] = Uo_b;  ca.n[5] = HH * HH;
    ca.src[6] = Uu;  ca.dst[6] = Uu_b;  ca.n[6] = HH * HH;
    ca.src[7] = WfK; ca.dst[7] = WfK_b; ca.n[7] = KK * HH * HH;

    cvt_k<<<dim3(KK * HH * HH / 1024, 8), dim3(256), 0, stream>>>(ca);
    child_gates_k<<<dim3(1024), dim3(512), 0, stream>>>(
        cx, Wi_b, Wo_b, Wu_b, bi, bo, bu, cc, hs);
    root_k<<<dim3(BB / 64, 2), dim3(256), 0, stream>>>(
        x, Wi_b, Wf_b, Wo_b, Wu_b, Ui_b, Uo_b, Uu_b, WfK_b,
        bi, bf_, bo, bu, cc, hs, (float*)d_out);
}

// Round 4
// 493.468 us; speedup vs baseline: 1.5102x; 1.4101x over previous
//
#include <hip/hip_runtime.h>
#include <hip/hip_bf16.h>

// NaryTreeLSTM  B=32768, K=4, I=256, H=256
// DTYPE MODEL (verified): inputs fp32, outputs fp32, bf16-scale threshold
// => bf16 MFMA pipeline, fp32 accum, fp32 out stores.
//
// ROUND-9: root_k structural rewrite: A-in-LDS, 4x B-frag reuse.
//   R8 evidence (VGPR=84, MfmaUtil 5.1%, 1:1 weight-load:MFMA) = latency-
//   bound with zero weight reuse. New root: block = 4 waves x 16 cols =
//   64 cols, 64 rows; x+hsum staged ONCE into 64KB swizzled LDS (single
//   barrier per kernel); each wave computes 4 row-tiles from LDS, so each
//   weight frag from L2 feeds 4 MFMAs (pass1) / 2 (pass2 rt-pair halves).
//   XOR swizzle byte^=(row&7)<<4 -> conflict-free ds_read_b128 (2-way max).
//   launch_bounds(256,2): 256-reg budget, LDS caps at 2 blocks/CU.
// child: byte-identical to R5-R8 (~310us); its counters surface next round.
//
// ws: cc [B][H][K] bf16, hsum [B][H] bf16, bf16 weight copies.

#define BB 32768
#define KK 4
#define II 256
#define HH 256

typedef __bf16 bf16x8 __attribute__((ext_vector_type(8)));
typedef __bf16 bf16x4 __attribute__((ext_vector_type(4)));
typedef float f32x4 __attribute__((ext_vector_type(4)));

#define MFMA16(a, b, c) __builtin_amdgcn_mfma_f32_16x16x32_bf16(a, b, c, 0, 0, 0)

static __device__ __forceinline__ float fsig(float x) {
    return 1.0f / (1.0f + __expf(-x));
}
static __device__ __forceinline__ float ftanhf(float x) {
    float e = __expf(2.0f * x);
    return 1.0f - 2.0f / (e + 1.0f);
}

static __device__ __forceinline__ bf16x8 cvt8v(float4 f0, float4 f1) {
    bf16x8 v;
    v[0] = (__bf16)f0.x; v[1] = (__bf16)f0.y; v[2] = (__bf16)f0.z; v[3] = (__bf16)f0.w;
    v[4] = (__bf16)f1.x; v[5] = (__bf16)f1.y; v[6] = (__bf16)f1.z; v[7] = (__bf16)f1.w;
    return v;
}
static __device__ __forceinline__ bf16x8 cvt8(const float* __restrict__ p) {
    return cvt8v(((const float4*)p)[0], ((const float4*)p)[1]);
}

// ---------------- Kernel 0: fp32 -> bf16 weight conversion ----------------
struct CvtArgs {
    const float* src[8];
    __bf16* dst[8];
    int n[8];
};
__global__ __launch_bounds__(256) void cvt_k(CvtArgs a) {
    const int t = blockIdx.y;
    const int i = (blockIdx.x * 256 + threadIdx.x) * 4;
    if (i < a.n[t]) {
        float4 f = *(const float4*)(a.src[t] + i);
        bf16x4 v;
        v[0] = (__bf16)f.x; v[1] = (__bf16)f.y; v[2] = (__bf16)f.z; v[3] = (__bf16)f.w;
        *(bf16x4*)(a.dst[t] + i) = v;
    }
}

// ---------------- Kernel 1: child gates, streaming ----------------
// grid.x = 1024 linear: rowchunk = bid>>1 (256 child rows), cthalf = bid&1.
// LDS row stride 264 elems (528 B): 16B-superbank stride 33 -> uniform
// 8-lane/superbank for both ds_write (staging) and ds_read_b128 (frags).
#define ROWSTR 264
__global__ __launch_bounds__(512, 2) void child_gates_k(
    const float* __restrict__ child_x,
    const __bf16* __restrict__ Wi, const __bf16* __restrict__ Wo,
    const __bf16* __restrict__ Wu,
    const float* __restrict__ bi, const float* __restrict__ bo,
    const float* __restrict__ bu,
    __bf16* __restrict__ cc, __bf16* __restrict__ hsum)
{
    const int tid  = threadIdx.x;
    const int wave = tid >> 6;
    const int lane = tid & 63;
    const int l16  = lane & 15;
    const int quad = lane >> 4;
    const int rowchunk = blockIdx.x >> 1;           // 256 child rows each
    const int ct   = (blockIdx.x & 1) * 8 + wave;   // this wave's col-tile
    const int n    = ct * 16 + l16;

    // --- weight fragments for this ct, held for the whole kernel (96 VGPR)
    bf16x8 w[3][8];
    {
        const int base = n * II + quad * 8;
#pragma unroll
        for (int ks = 0; ks < 8; ++ks) {
            w[0][ks] = *(const bf16x8*)(Wi + base + ks * 32);
            w[1][ks] = *(const bf16x8*)(Wo + base + ks * 32);
            w[2][ks] = *(const bf16x8*)(Wu + base + ks * 32);
        }
    }
    const float bin = bi[n], bon = bo[n], bun = bu[n];

    __shared__ __bf16 As[2][16 * ROWSTR];

    // staging map: 512 thr, thread -> (row = tid>>5, col8 = (tid&31)*8)
    const int srow = tid >> 5;
    const int scol = (tid & 31) * 8;
    const float* gbase = child_x + ((size_t)rowchunk * 256 + srow) * II + scol;

    float4 f0 = ((const float4*)gbase)[0];
    float4 f1 = ((const float4*)gbase)[1];
    *(bf16x8*)(&As[0][srow * ROWSTR + scol]) = cvt8v(f0, f1);
    __syncthreads();

    for (int t = 0; t < 16; ++t) {
        float4 g0, g1;
        if (t < 15) {   // issue t+1 global loads now; consume after compute
            const float* gp = gbase + (size_t)(t + 1) * 16 * II;
            g0 = ((const float4*)gp)[0];
            g1 = ((const float4*)gp)[1];
        }

        // --- compute tile t from LDS
        const __bf16* ap = &As[t & 1][l16 * ROWSTR + quad * 8];
        f32x4 ai = {0.f,0.f,0.f,0.f}, ao = {0.f,0.f,0.f,0.f}, au = {0.f,0.f,0.f,0.f};
#pragma unroll
        for (int ks = 0; ks < 8; ++ks) {
            bf16x8 a = *(const bf16x8*)(ap + ks * 32);
            ai = MFMA16(a, w[0][ks], ai);
            ao = MFMA16(a, w[1][ks], ao);
            au = MFMA16(a, w[2][ks], au);
        }

        // --- epilogue: lane's 4 regs = 4 children of b = rowchunk*64+t*4+quad
        {
            const int b = rowchunk * 64 + t * 4 + quad;
            float chs = 0.f;
            bf16x4 ccv4;
#pragma unroll
            for (int r = 0; r < 4; ++r) {
                float civ = fsig(ai[r] + bin);
                float cov = fsig(ao[r] + bon);
                float cuv = ftanhf(au[r] + bun);
                float ccv = civ * cuv;
                chs += cov * ftanhf(ccv);
                ccv4[r] = (__bf16)ccv;
            }
            *(bf16x4*)(cc + ((size_t)b * HH + n) * KK) = ccv4;
            hsum[(size_t)b * HH + n] = (__bf16)chs;
        }

        if (t < 15)
            *(bf16x8*)(&As[(t + 1) & 1][srow * ROWSTR + scol]) = cvt8v(g0, g1);
        __syncthreads();
    }
}

// ---------------- Kernel 2: root gates, A-in-LDS ----------------
// Block: 256 thr = 4 waves; block tile = 64 rows x 64 cols (wave ct =
// by*4+wave, 16 cols each). x+hsum staged once into swizzled LDS (one
// barrier), then each wave: pass1 (i,o,u; 6 wloads : 24 MFMA per ks),
// pass2 in rt-pair halves (5 wloads : 10 MFMA per ks). Weight frags from
// global (L2-hot) with 4x/2x register reuse across row-tiles.
__global__ __launch_bounds__(256, 2) void root_k(
    const float* __restrict__ x,
    const __bf16* __restrict__ Wi, const __bf16* __restrict__ Wf,
    const __bf16* __restrict__ Wo, const __bf16* __restrict__ Wu,
    const __bf16* __restrict__ Ui, const __bf16* __restrict__ Uo,
    const __bf16* __restrict__ Uu, const __bf16* __restrict__ WfK,
    const float* __restrict__ bi, const float* __restrict__ bf_,
    const float* __restrict__ bo, const float* __restrict__ bu,
    const __bf16* __restrict__ cc, const __bf16* __restrict__ hsum,
    float* __restrict__ out)
{
    const int tid  = threadIdx.x;
    const int lane = tid & 63;
    const int wave = tid >> 6;
    const int l16  = lane & 15;
    const int quad = lane >> 4;
    const int row0 = blockIdx.x * 64;               // block's 64 b-rows
    const int ct   = blockIdx.y * 4 + wave;         // wave's 16 cols
    const int n    = ct * 16 + l16;

    // swizzled A-planes: row stride 512B, byte ^= (row&7)<<4
    __shared__ __bf16 xs[64 * 256];
    __shared__ __bf16 hsl[64 * 256];

    // ---- stage x (fp32 -> bf16, coalesced float4 per lane) ----
    {
        const float* xg = x + (size_t)row0 * II;
#pragma unroll
        for (int p = 0; p < 16; ++p) {
            const int e = p * 1024 + tid * 4;       // elem in 64x256
            float4 f = *(const float4*)(xg + e);
            bf16x4 v;
            v[0] = (__bf16)f.x; v[1] = (__bf16)f.y;
            v[2] = (__bf16)f.z; v[3] = (__bf16)f.w;
            const int r = e >> 8, c = e & 255;
            int off = r * 512 + c * 2;
            off ^= (r & 7) << 4;
            *(bf16x4*)((char*)xs + off) = v;
        }
        const __bf16* hg = hsum + (size_t)row0 * HH;
#pragma unroll
        for (int p = 0; p < 8; ++p) {
            const int u = p * 256 + tid;            // 16B unit in 64x256
            bf16x8 v = *(const bf16x8*)(hg + u * 8);
            const int r = u >> 5, c = (u & 31) * 8;
            int off = r * 512 + c * 2;
            off ^= (r & 7) << 4;
            *(bf16x8*)((char*)hsl + off) = v;
        }
    }
    __syncthreads();    // the only barrier; LDS read-only afterwards

    const float bin = bi[n], bfn = bf_[n], bon = bo[n], bun = bu[n];
    const int wo = n * II + quad * 8;
    const int cbase = quad * 8;                     // lane's k-chunk base

#define LDA(plane, rt, ks) \
    (*(const bf16x8*)((const char*)(plane) + \
        ((((rt) * 16 + l16) * 512 + ((cbase) + (ks) * 32) * 2) ^ \
         ((((rt) * 16 + l16) & 7) << 4))))

    // ---- pass 1: i, o, u over 4 row-tiles ----
    f32x4 ai[4], ao[4], au[4];
    {
        const f32x4 z = {0.f, 0.f, 0.f, 0.f};
#pragma unroll
        for (int rt = 0; rt < 4; ++rt) { ai[rt] = z; ao[rt] = z; au[rt] = z; }
    }
#pragma unroll
    for (int ks = 0; ks < 8; ++ks) {
        const int o = wo + ks * 32;
        bf16x8 bwi = *(const bf16x8*)(Wi + o);
        bf16x8 bui = *(const bf16x8*)(Ui + o);
        bf16x8 bwo = *(const bf16x8*)(Wo + o);
        bf16x8 buo = *(const bf16x8*)(Uo + o);
        bf16x8 bwu = *(const bf16x8*)(Wu + o);
        bf16x8 buu = *(const bf16x8*)(Uu + o);
#pragma unroll
        for (int rt = 0; rt < 4; ++rt) {
            bf16x8 a = LDA(xs, rt, ks);
            bf16x8 h = LDA(hsl, rt, ks);
            ai[rt] = MFMA16(a, bwi, ai[rt]);
            ai[rt] = MFMA16(h, bui, ai[rt]);
            ao[rt] = MFMA16(a, bwo, ao[rt]);
            ao[rt] = MFMA16(h, buo, ao[rt]);
            au[rt] = MFMA16(a, bwu, au[rt]);
            au[rt] = MFMA16(h, buu, au[rt]);
        }
    }
    // nonlinearities; keep only i*u and o
    f32x4 cpart[4], ovv[4];
#pragma unroll
    for (int rt = 0; rt < 4; ++rt)
#pragma unroll
        for (int r = 0; r < 4; ++r) {
            const float iv = fsig(ai[rt][r] + bin);
            const float ov = fsig(ao[rt][r] + bon);
            const float uv = ftanhf(au[rt][r] + bun);
            cpart[rt][r] = iv * uv;
            ovv[rt][r]   = ov;
        }

    // ---- pass 2: f-family, two rt-pair halves ----
#pragma unroll
    for (int h2 = 0; h2 < 2; ++h2) {
        // prefetch cc gathers for this half's 32 rows
        bf16x4 cv4[2][4];
#pragma unroll
        for (int rt2 = 0; rt2 < 2; ++rt2)
#pragma unroll
            for (int r = 0; r < 4; ++r) {
                const int b = row0 + (h2 * 2 + rt2) * 16 + quad * 4 + r;
                cv4[rt2][r] = *(const bf16x4*)(cc + ((size_t)b * HH + n) * KK);
            }

        f32x4 axf[2], af0[2], af1[2], af2[2], af3[2];
        {
            const f32x4 z = {0.f, 0.f, 0.f, 0.f};
#pragma unroll
            for (int rt2 = 0; rt2 < 2; ++rt2) {
                axf[rt2] = z; af0[rt2] = z; af1[rt2] = z;
                af2[rt2] = z; af3[rt2] = z;
            }
        }
#pragma unroll
        for (int ks = 0; ks < 8; ++ks) {
            const int o = wo + ks * 32;
            bf16x8 bwf = *(const bf16x8*)(Wf + o);
            bf16x8 bk0 = *(const bf16x8*)(WfK + 0 * HH * II + o);
            bf16x8 bk1 = *(const bf16x8*)(WfK + 1 * HH * II + o);
            bf16x8 bk2 = *(const bf16x8*)(WfK + 2 * HH * II + o);
            bf16x8 bk3 = *(const bf16x8*)(WfK + 3 * HH * II + o);
#pragma unroll
            for (int rt2 = 0; rt2 < 2; ++rt2) {
                const int rt = h2 * 2 + rt2;
                bf16x8 a = LDA(xs, rt, ks);
                bf16x8 h = LDA(hsl, rt, ks);
                axf[rt2] = MFMA16(a, bwf, axf[rt2]);
                af0[rt2] = MFMA16(h, bk0, af0[rt2]);
                af1[rt2] = MFMA16(h, bk1, af1[rt2]);
                af2[rt2] = MFMA16(h, bk2, af2[rt2]);
                af3[rt2] = MFMA16(h, bk3, af3[rt2]);
            }
        }

        // epilogue for this half: fp32 stores
#pragma unroll
        for (int rt2 = 0; rt2 < 2; ++rt2) {
            const int rt = h2 * 2 + rt2;
#pragma unroll
            for (int r = 0; r < 4; ++r) {
                const int b = row0 + rt * 16 + quad * 4 + r;
                const float xfv = axf[rt2][r] + bfn;
                float cv = cpart[rt][r];
                cv += fsig(xfv + af0[rt2][r]) * (float)cv4[rt2][r][0];
                cv += fsig(xfv + af1[rt2][r]) * (float)cv4[rt2][r][1];
                cv += fsig(xfv + af2[rt2][r]) * (float)cv4[rt2][r][2];
                cv += fsig(xfv + af3[rt2][r]) * (float)cv4[rt2][r][3];
                const float hv = ovv[rt][r] * ftanhf(cv);
                out[(size_t)b * HH + n] = hv;                    // h
                out[(size_t)BB * HH + (size_t)b * HH + n] = cv;  // c
            }
        }
    }
#undef LDA
}

extern "C" void kernel_launch(void* const* d_in, const int* in_sizes, int n_in,
                              void* d_out, int out_size, void* d_ws, size_t ws_size,
                              hipStream_t stream) {
    const float* x    = (const float*)d_in[0];
    const float* cx   = (const float*)d_in[1];
    const float* Wi   = (const float*)d_in[2];
    const float* bi   = (const float*)d_in[3];
    const float* Wf   = (const float*)d_in[4];
    const float* bf_  = (const float*)d_in[5];
    const float* Wo   = (const float*)d_in[6];
    const float* bo   = (const float*)d_in[7];
    const float* Wu   = (const float*)d_in[8];
    const float* bu   = (const float*)d_in[9];
    const float* Ui   = (const float*)d_in[10];
    const float* Uo   = (const float*)d_in[11];
    const float* Uu   = (const float*)d_in[12];
    const float* WfK  = (const float*)d_in[13];

    __bf16* cc = (__bf16*)d_ws;                     // [B][H][K]
    __bf16* hs = cc + (size_t)BB * KK * HH;         // [B][H]
    __bf16* wb = hs + (size_t)BB * HH;              // bf16 weight block
    __bf16 *Wi_b = wb,            *Wf_b = Wi_b + HH * II, *Wo_b = Wf_b + HH * II,
           *Wu_b = Wo_b + HH * II, *Ui_b = Wu_b + HH * II, *Uo_b = Ui_b + HH * HH,
           *Uu_b = Uo_b + HH * HH, *WfK_b = Uu_b + HH * HH;  // WfK: K*H*H

    CvtArgs ca;
    ca.src[0] = Wi;  ca.dst[0] = Wi_b;  ca.n[0] = HH * II;
    ca.src[1] = Wf;  ca.dst[1] = Wf_b;  ca.n[1] = HH * II;
    ca.src[2] = Wo;  ca.dst[2] = Wo_b;  ca.n[2] = HH * II;
    ca.src[3] = Wu;  ca.dst[3] = Wu_b;  ca.n[3] = HH * II;
    ca.src[4] = Ui;  ca.dst[4] = Ui_b;  ca.n[4] = HH * HH;
    ca.src[5] = Uo;  ca.dst[5] = Uo_b;  ca.n[5] = HH * HH;
    ca.src[6] = Uu;  ca.dst[6] = Uu_b;  ca.n[6] = HH * HH;
    ca.src[7] = WfK; ca.dst[7] = WfK_b; ca.n[7] = KK * HH * HH;

    cvt_k<<<dim3(KK * HH * HH / 1024, 8), dim3(256), 0, stream>>>(ca);
    child_gates_k<<<dim3(1024), dim3(512), 0, stream>>>(
        cx, Wi_b, Wo_b, Wu_b, bi, bo, bu, cc, hs);
    root_k<<<dim3(BB / 64, 4), dim3(256), 0, stream>>>(
        x, Wi_b, Wf_b, Wo_b, Wu_b, Ui_b, Uo_b, Uu_b, WfK_b,
        bi, bf_, bo, bu, cc, hs, (float*)d_out);
}